// Round 4
// baseline (69.426 us; speedup 1.0000x reference)
//
#include <hip/hip_runtime.h>
#include <hip/hip_bf16.h>

#define B_ 8
#define T_ 2048
#define V_ 256
#define D_ 512
#define LEFT_ 16
#define BT 8                       // tokens per block
#define NROWS (BT + LEFT_ - 1)     // 23 staged rows

__device__ __forceinline__ float bf_lo(unsigned u) {
    union { unsigned u; float f; } c; c.u = u << 16; return c.f;
}
__device__ __forceinline__ float bf_hi(unsigned u) {
    union { unsigned u; float f; } c; c.u = u & 0xffff0000u; return c.f;
}
__device__ __forceinline__ unsigned pack_bf2(float a, float b) {
    __hip_bfloat162 h = __float22bfloat162_rn(make_float2(a, b));
    union { __hip_bfloat162 h; unsigned u; } c; c.h = h; return c.u;
}

__global__ __launch_bounds__(256, 6)
void attn_cell_kernel(const int* __restrict__ symbols,
                      const float* __restrict__ encodings,
                      const float* __restrict__ M,
                      const float* __restrict__ C,
                      float* __restrict__ out,      // (B,T,1024)
                      float* __restrict__ p_out) {  // (B,T,16)
    // 23 rows x 512 bf16 = 23.5 KB; p_s 512 B  -> ~24 KB: 6 blocks/CU
    __shared__ __align__(16) unsigned rows[NROWS][D_ / 2];
    __shared__ __align__(16) float p_s[BT][16];

    const int tid  = threadIdx.x;
    const int lane = tid & 63;
    const int w    = tid >> 6;

    const int blk = blockIdx.x;
    const int b   = blk >> 8;             // T_/BT = 256 blocks per batch row
    const int t0  = (blk & 255) * BT;
    const int* symrow = symbols + b * T_;

    // ---- stage M rows (f32 -> bf16), unrolled so loads pipeline ----
    #pragma unroll 4
    for (int i = tid; i < NROWS * (D_ / 4); i += 256) {   // 23*128 = 2944 granules
        const int r = i >> 7;
        const int c = i & 127;
        int pos = t0 - (LEFT_ - 1) + r;
        if (pos < 0) pos = 0;
        const float4 v = reinterpret_cast<const float4*>(M + (size_t)symrow[pos] * D_)[c];
        *reinterpret_cast<uint2*>(&rows[r][c * 2]) =
            make_uint2(pack_bf2(v.x, v.y), pack_bf2(v.z, v.w));
    }
    __syncthreads();

    // bit-reversed 4-bit lane id: the ctx row this lane ends up owning after the fold
    const int l4 = lane & 15;
    const int rl = ((l4 & 1) << 3) | ((l4 & 2) << 1) | ((l4 & 4) >> 1) | ((l4 & 8) >> 3);

    // ---- phase 1: scores + folding reduce + group softmax + enc passthrough ----
    #pragma unroll
    for (int i = 0; i < 2; ++i) {
        const int lt = w + i * 4;          // 2 tokens per wave
        const int t  = t0 + lt;
        const size_t ebase = ((size_t)(b * T_ + t)) * D_ + (size_t)lane * 8;
        const float4 e0 = *reinterpret_cast<const float4*>(encodings + ebase);
        const float4 e1 = *reinterpret_cast<const float4*>(encodings + ebase + 4);

        float s[16];
        #pragma unroll
        for (int l = 0; l < 16; ++l) {
            const uint4 m = *reinterpret_cast<const uint4*>(&rows[lt + l][lane * 4]);
            s[l] = bf_lo(m.x) * e0.x + bf_hi(m.x) * e0.y
                 + bf_lo(m.y) * e0.z + bf_hi(m.y) * e0.w
                 + bf_lo(m.z) * e1.x + bf_hi(m.z) * e1.y
                 + bf_lo(m.w) * e1.z + bf_hi(m.w) * e1.w;
        }

        // folding butterfly: 15 shfl, value count 16 -> 1
        #pragma unroll
        for (int k = 0; k < 8; ++k) {   // xor 1
            const float lo = s[k], hi = s[k + 8];
            const float sd = (lane & 1) ? lo : hi;
            const float rv = __shfl_xor(sd, 1);
            s[k] = (lane & 1) ? hi + rv : lo + rv;
        }
        #pragma unroll
        for (int k = 0; k < 4; ++k) {   // xor 2
            const float lo = s[k], hi = s[k + 4];
            const float sd = (lane & 2) ? lo : hi;
            const float rv = __shfl_xor(sd, 2);
            s[k] = (lane & 2) ? hi + rv : lo + rv;
        }
        #pragma unroll
        for (int k = 0; k < 2; ++k) {   // xor 4
            const float lo = s[k], hi = s[k + 2];
            const float sd = (lane & 4) ? lo : hi;
            const float rv = __shfl_xor(sd, 4);
            s[k] = (lane & 4) ? hi + rv : lo + rv;
        }
        {                               // xor 8
            const float lo = s[0], hi = s[1];
            const float sd = (lane & 8) ? lo : hi;
            const float rv = __shfl_xor(sd, 8);
            s[0] = (lane & 8) ? hi + rv : lo + rv;
        }
        float v = s[0];
        v += __shfl_xor(v, 16);
        v += __shfl_xor(v, 32);
        // lane now holds the full score for ctx row rl of token t

        float mx = v;
        mx = fmaxf(mx, __shfl_xor(mx, 1));
        mx = fmaxf(mx, __shfl_xor(mx, 2));
        mx = fmaxf(mx, __shfl_xor(mx, 4));
        mx = fmaxf(mx, __shfl_xor(mx, 8));
        const float e = __expf(v - mx);
        float sum = e;
        sum += __shfl_xor(sum, 1);
        sum += __shfl_xor(sum, 2);
        sum += __shfl_xor(sum, 4);
        sum += __shfl_xor(sum, 8);
        const float p = e / sum;

        if (lane < 16) {
            p_out[((size_t)(b * T_ + t)) * 16 + rl] = p;
            p_s[lt][rl] = p;
        }

        // enc passthrough: out[b,t,512:1024] = enc (exact f32)
        float4* ob = reinterpret_cast<float4*>(out + ((size_t)(b * T_ + t)) * 1024 + D_ + (size_t)lane * 8);
        ob[0] = e0; ob[1] = e1;
    }
    __syncthreads();

    // ---- stage C rows (reuse LDS), unrolled ----
    #pragma unroll 4
    for (int i = tid; i < NROWS * (D_ / 4); i += 256) {
        const int r = i >> 7;
        const int c = i & 127;
        int pos = t0 - (LEFT_ - 1) + r;
        if (pos < 0) pos = 0;
        const float4 v = reinterpret_cast<const float4*>(C + (size_t)symrow[pos] * D_)[c];
        *reinterpret_cast<uint2*>(&rows[r][c * 2]) =
            make_uint2(pack_bf2(v.x, v.y), pack_bf2(v.z, v.w));
    }
    __syncthreads();

    // ---- phase 2: compressed = sum_l p_l * C_row_l ----
    #pragma unroll
    for (int i = 0; i < 2; ++i) {
        const int lt = w + i * 4;
        const int t  = t0 + lt;
        const float4 q0 = *reinterpret_cast<const float4*>(&p_s[lt][0]);
        const float4 q1 = *reinterpret_cast<const float4*>(&p_s[lt][4]);
        const float4 q2 = *reinterpret_cast<const float4*>(&p_s[lt][8]);
        const float4 q3 = *reinterpret_cast<const float4*>(&p_s[lt][12]);
        const float pw[16] = { q0.x, q0.y, q0.z, q0.w, q1.x, q1.y, q1.z, q1.w,
                               q2.x, q2.y, q2.z, q2.w, q3.x, q3.y, q3.z, q3.w };

        float4 a0 = make_float4(0.f, 0.f, 0.f, 0.f);
        float4 a1 = make_float4(0.f, 0.f, 0.f, 0.f);
        #pragma unroll
        for (int l = 0; l < 16; ++l) {
            const uint4 c4 = *reinterpret_cast<const uint4*>(&rows[lt + l][lane * 4]);
            const float pl = pw[l];
            a0.x += pl * bf_lo(c4.x); a0.y += pl * bf_hi(c4.x);
            a0.z += pl * bf_lo(c4.y); a0.w += pl * bf_hi(c4.y);
            a1.x += pl * bf_lo(c4.z); a1.y += pl * bf_hi(c4.z);
            a1.z += pl * bf_lo(c4.w); a1.w += pl * bf_hi(c4.w);
        }
        float4* ob = reinterpret_cast<float4*>(out + ((size_t)(b * T_ + t)) * 1024 + (size_t)lane * 8);
        ob[0] = a0; ob[1] = a1;
    }
}

extern "C" void kernel_launch(void* const* d_in, const int* in_sizes, int n_in,
                              void* d_out, int out_size, void* d_ws, size_t ws_size,
                              hipStream_t stream) {
    const int*   symbols   = (const int*)d_in[0];
    const float* encodings = (const float*)d_in[1];
    const float* M         = (const float*)d_in[2];
    const float* C         = (const float*)d_in[3];
    float* out   = (float*)d_out;
    float* p_out = out + (size_t)B_ * T_ * 1024;   // concat order: output, then p

    dim3 grid(B_ * (T_ / BT));
    attn_cell_kernel<<<grid, 256, 0, stream>>>(symbols, encodings, M, C, out, p_out);
}

// Round 5
// 54.731 us; speedup vs baseline: 1.2685x; 1.2685x over previous
//
#include <hip/hip_runtime.h>
#include <hip/hip_bf16.h>

#define B_ 8
#define T_ 2048
#define V_ 256
#define D_ 512
#define LEFT_ 16
#define BT 16                      // tokens per block
#define NROWS (BT + LEFT_ - 1)     // 31 staged rows

__device__ __forceinline__ float bf_lo(unsigned u) {
    union { unsigned u; float f; } c; c.u = u << 16; return c.f;
}
__device__ __forceinline__ float bf_hi(unsigned u) {
    union { unsigned u; float f; } c; c.u = u & 0xffff0000u; return c.f;
}
__device__ __forceinline__ unsigned pack_bf2(float a, float b) {
    __hip_bfloat162 h = __float22bfloat162_rn(make_float2(a, b));
    union { __hip_bfloat162 h; unsigned u; } c; c.h = h; return c.u;
}

__global__ __launch_bounds__(256, 5)
void attn_cell_kernel(const int* __restrict__ symbols,
                      const float* __restrict__ encodings,
                      const float* __restrict__ M,
                      const float* __restrict__ C,
                      float* __restrict__ out,      // (B,T,1024)
                      float* __restrict__ p_out) {  // (B,T,16)
    // 31 rows x 512 bf16 = 31744 B + p_s 1024 B = 32768 B -> 5 blocks/CU
    __shared__ __align__(16) unsigned rows[NROWS][D_ / 2];
    __shared__ __align__(16) float p_s[BT][16];

    const int tid  = threadIdx.x;
    const int lane = tid & 63;
    const int w    = tid >> 6;

    const int blk = blockIdx.x;
    const int b   = blk >> 7;             // T_/BT = 128 blocks per batch row
    const int t0  = (blk & 127) * BT;
    const int* symrow = symbols + b * T_;

    // ---- stage M rows (f32 -> bf16), unrolled so gather loads pipeline ----
    #pragma unroll 4
    for (int i = tid; i < NROWS * (D_ / 4); i += 256) {   // 31*128 = 3968 granules
        const int r = i >> 7;
        const int c = i & 127;
        int pos = t0 - (LEFT_ - 1) + r;
        if (pos < 0) pos = 0;
        const float4 v = reinterpret_cast<const float4*>(M + (size_t)symrow[pos] * D_)[c];
        *reinterpret_cast<uint2*>(&rows[r][c * 2]) =
            make_uint2(pack_bf2(v.x, v.y), pack_bf2(v.z, v.w));
    }
    __syncthreads();

    // bit-reversed 4-bit lane id: the ctx row this lane owns after the fold
    const int l4 = lane & 15;
    const int rl = ((l4 & 1) << 3) | ((l4 & 2) << 1) | ((l4 & 4) >> 1) | ((l4 & 8) >> 3);

    // ---- phase 1: scores + folding reduce + group softmax + enc passthrough ----
    #pragma unroll
    for (int i = 0; i < 4; ++i) {
        const int lt = w + i * 4;          // 4 tokens per wave
        const int t  = t0 + lt;
        const size_t ebase = ((size_t)(b * T_ + t)) * D_ + (size_t)lane * 8;
        const float4 e0 = *reinterpret_cast<const float4*>(encodings + ebase);
        const float4 e1 = *reinterpret_cast<const float4*>(encodings + ebase + 4);

        float s[16];
        #pragma unroll
        for (int l = 0; l < 16; ++l) {
            const uint4 m = *reinterpret_cast<const uint4*>(&rows[lt + l][lane * 4]);
            s[l] = bf_lo(m.x) * e0.x + bf_hi(m.x) * e0.y
                 + bf_lo(m.y) * e0.z + bf_hi(m.y) * e0.w
                 + bf_lo(m.z) * e1.x + bf_hi(m.z) * e1.y
                 + bf_lo(m.w) * e1.z + bf_hi(m.w) * e1.w;
        }

        // folding butterfly: 15 shfl, value count 16 -> 1
        #pragma unroll
        for (int k = 0; k < 8; ++k) {   // xor 1
            const float lo = s[k], hi = s[k + 8];
            const float sd = (lane & 1) ? lo : hi;
            const float rv = __shfl_xor(sd, 1);
            s[k] = (lane & 1) ? hi + rv : lo + rv;
        }
        #pragma unroll
        for (int k = 0; k < 4; ++k) {   // xor 2
            const float lo = s[k], hi = s[k + 4];
            const float sd = (lane & 2) ? lo : hi;
            const float rv = __shfl_xor(sd, 2);
            s[k] = (lane & 2) ? hi + rv : lo + rv;
        }
        #pragma unroll
        for (int k = 0; k < 2; ++k) {   // xor 4
            const float lo = s[k], hi = s[k + 2];
            const float sd = (lane & 4) ? lo : hi;
            const float rv = __shfl_xor(sd, 4);
            s[k] = (lane & 4) ? hi + rv : lo + rv;
        }
        {                               // xor 8
            const float lo = s[0], hi = s[1];
            const float sd = (lane & 8) ? lo : hi;
            const float rv = __shfl_xor(sd, 8);
            s[0] = (lane & 8) ? hi + rv : lo + rv;
        }
        float v = s[0];
        v += __shfl_xor(v, 16);
        v += __shfl_xor(v, 32);
        // lane now holds the full score for ctx row rl of token t

        float mx = v;
        mx = fmaxf(mx, __shfl_xor(mx, 1));
        mx = fmaxf(mx, __shfl_xor(mx, 2));
        mx = fmaxf(mx, __shfl_xor(mx, 4));
        mx = fmaxf(mx, __shfl_xor(mx, 8));
        const float e = __expf(v - mx);
        float sum = e;
        sum += __shfl_xor(sum, 1);
        sum += __shfl_xor(sum, 2);
        sum += __shfl_xor(sum, 4);
        sum += __shfl_xor(sum, 8);
        const float p = e / sum;

        if (lane < 16) {
            p_out[((size_t)(b * T_ + t)) * 16 + rl] = p;
            p_s[lt][rl] = p;
        }

        // enc passthrough: out[b,t,512:1024] = enc (exact f32)
        float4* ob = reinterpret_cast<float4*>(out + ((size_t)(b * T_ + t)) * 1024 + D_ + (size_t)lane * 8);
        ob[0] = e0; ob[1] = e1;
    }
    __syncthreads();

    // ---- stage C rows (reuse LDS), unrolled ----
    #pragma unroll 4
    for (int i = tid; i < NROWS * (D_ / 4); i += 256) {
        const int r = i >> 7;
        const int c = i & 127;
        int pos = t0 - (LEFT_ - 1) + r;
        if (pos < 0) pos = 0;
        const float4 v = reinterpret_cast<const float4*>(C + (size_t)symrow[pos] * D_)[c];
        *reinterpret_cast<uint2*>(&rows[r][c * 2]) =
            make_uint2(pack_bf2(v.x, v.y), pack_bf2(v.z, v.w));
    }
    __syncthreads();

    // ---- phase 2: compressed = sum_l p_l * C_row_l ----
    #pragma unroll
    for (int i = 0; i < 4; ++i) {
        const int lt = w + i * 4;
        const int t  = t0 + lt;
        const float4 q0 = *reinterpret_cast<const float4*>(&p_s[lt][0]);
        const float4 q1 = *reinterpret_cast<const float4*>(&p_s[lt][4]);
        const float4 q2 = *reinterpret_cast<const float4*>(&p_s[lt][8]);
        const float4 q3 = *reinterpret_cast<const float4*>(&p_s[lt][12]);
        const float pw[16] = { q0.x, q0.y, q0.z, q0.w, q1.x, q1.y, q1.z, q1.w,
                               q2.x, q2.y, q2.z, q2.w, q3.x, q3.y, q3.z, q3.w };

        float4 a0 = make_float4(0.f, 0.f, 0.f, 0.f);
        float4 a1 = make_float4(0.f, 0.f, 0.f, 0.f);
        #pragma unroll
        for (int l = 0; l < 16; ++l) {
            const uint4 c4 = *reinterpret_cast<const uint4*>(&rows[lt + l][lane * 4]);
            const float pl = pw[l];
            a0.x += pl * bf_lo(c4.x); a0.y += pl * bf_hi(c4.x);
            a0.z += pl * bf_lo(c4.y); a0.w += pl * bf_hi(c4.y);
            a1.x += pl * bf_lo(c4.z); a1.y += pl * bf_hi(c4.z);
            a1.z += pl * bf_lo(c4.w); a1.w += pl * bf_hi(c4.w);
        }
        float4* ob = reinterpret_cast<float4*>(out + ((size_t)(b * T_ + t)) * 1024 + (size_t)lane * 8);
        ob[0] = a0; ob[1] = a1;
    }
}

extern "C" void kernel_launch(void* const* d_in, const int* in_sizes, int n_in,
                              void* d_out, int out_size, void* d_ws, size_t ws_size,
                              hipStream_t stream) {
    const int*   symbols   = (const int*)d_in[0];
    const float* encodings = (const float*)d_in[1];
    const float* M         = (const float*)d_in[2];
    const float* C         = (const float*)d_in[3];
    float* out   = (float*)d_out;
    float* p_out = out + (size_t)B_ * T_ * 1024;   // concat order: output, then p

    dim3 grid(B_ * (T_ / BT));
    attn_cell_kernel<<<grid, 256, 0, stream>>>(symbols, encodings, M, C, out, p_out);
}

// Round 6
// 36.137 us; speedup vs baseline: 1.9212x; 1.5145x over previous
//
#include <hip/hip_runtime.h>
#include <hip/hip_bf16.h>

#define B_ 8
#define T_ 2048
#define V_ 256
#define D_ 512
#define LEFT_ 16
#define BT 16                      // tokens per block
#define NROWS 32                   // 31 needed + 1 pad row so staging is uniform

__device__ __forceinline__ float bf_lo(unsigned u) {
    union { unsigned u; float f; } c; c.u = u << 16; return c.f;
}
__device__ __forceinline__ float bf_hi(unsigned u) {
    union { unsigned u; float f; } c; c.u = u & 0xffff0000u; return c.f;
}
__device__ __forceinline__ unsigned pack_bf2(float a, float b) {
    __hip_bfloat162 h = __float22bfloat162_rn(make_float2(a, b));
    union { __hip_bfloat162 h; unsigned u; } c; c.h = h; return c.u;
}

__global__ __launch_bounds__(256, 4)
void attn_cell_kernel(const int* __restrict__ symbols,
                      const float* __restrict__ encodings,
                      const float* __restrict__ M,
                      const float* __restrict__ C,
                      float* __restrict__ out,      // (B,T,1024)
                      float* __restrict__ p_out) {  // (B,T,16)
    // 32 rows x 512 bf16 = 32 KB + p_s 1 KB = 33 KB -> 4 blocks/CU
    __shared__ __align__(16) unsigned rows[NROWS][D_ / 2];
    __shared__ __align__(16) float p_s[BT][16];

    const int tid  = threadIdx.x;
    const int lane = tid & 63;
    const int w    = tid >> 6;

    const int blk = blockIdx.x;
    const int b   = blk >> 7;             // T_/BT = 128 blocks per batch row
    const int t0  = (blk & 127) * BT;
    const int* symrow = symbols + b * T_;

    // ---- stage M rows (f32 -> bf16): 4096 granules = 16 uniform trips, unroll 4 ----
    #pragma unroll 4
    for (int i = tid; i < NROWS * (D_ / 4); i += 256) {
        const int r = i >> 7;
        const int c = i & 127;
        int pos = t0 - (LEFT_ - 1) + r;
        pos = max(pos, 0);
        pos = min(pos, T_ - 1);           // pad row 31 may run past the end
        const float4 v = reinterpret_cast<const float4*>(M + (size_t)symrow[pos] * D_)[c];
        *reinterpret_cast<uint2*>(&rows[r][c * 2]) =
            make_uint2(pack_bf2(v.x, v.y), pack_bf2(v.z, v.w));
    }
    __syncthreads();

    // bit-reversed 4-bit lane id: the ctx row this lane owns after the fold
    const int l4 = lane & 15;
    const int rl = ((l4 & 1) << 3) | ((l4 & 2) << 1) | ((l4 & 4) >> 1) | ((l4 & 8) >> 3);

    // ---- phase 1: scores + folding reduce + group softmax + enc passthrough ----
    #pragma unroll
    for (int i = 0; i < 4; ++i) {
        const int lt = w + i * 4;          // 4 tokens per wave
        const int t  = t0 + lt;
        const size_t ebase = ((size_t)(b * T_ + t)) * D_ + (size_t)lane * 8;
        const float4 e0 = *reinterpret_cast<const float4*>(encodings + ebase);
        const float4 e1 = *reinterpret_cast<const float4*>(encodings + ebase + 4);

        float s[16];
        #pragma unroll
        for (int l = 0; l < 16; ++l) {
            const uint4 m = *reinterpret_cast<const uint4*>(&rows[lt + l][lane * 4]);
            s[l] = bf_lo(m.x) * e0.x + bf_hi(m.x) * e0.y
                 + bf_lo(m.y) * e0.z + bf_hi(m.y) * e0.w
                 + bf_lo(m.z) * e1.x + bf_hi(m.z) * e1.y
                 + bf_lo(m.w) * e1.z + bf_hi(m.w) * e1.w;
        }

        // folding butterfly: 15 shfl, value count 16 -> 1
        #pragma unroll
        for (int k = 0; k < 8; ++k) {   // xor 1
            const float lo = s[k], hi = s[k + 8];
            const float sd = (lane & 1) ? lo : hi;
            const float rv = __shfl_xor(sd, 1);
            s[k] = (lane & 1) ? hi + rv : lo + rv;
        }
        #pragma unroll
        for (int k = 0; k < 4; ++k) {   // xor 2
            const float lo = s[k], hi = s[k + 4];
            const float sd = (lane & 2) ? lo : hi;
            const float rv = __shfl_xor(sd, 2);
            s[k] = (lane & 2) ? hi + rv : lo + rv;
        }
        #pragma unroll
        for (int k = 0; k < 2; ++k) {   // xor 4
            const float lo = s[k], hi = s[k + 2];
            const float sd = (lane & 4) ? lo : hi;
            const float rv = __shfl_xor(sd, 4);
            s[k] = (lane & 4) ? hi + rv : lo + rv;
        }
        {                               // xor 8
            const float lo = s[0], hi = s[1];
            const float sd = (lane & 8) ? lo : hi;
            const float rv = __shfl_xor(sd, 8);
            s[0] = (lane & 8) ? hi + rv : lo + rv;
        }
        float v = s[0];
        v += __shfl_xor(v, 16);
        v += __shfl_xor(v, 32);
        // lane now holds the full score for ctx row rl of token t

        float mx = v;
        mx = fmaxf(mx, __shfl_xor(mx, 1));
        mx = fmaxf(mx, __shfl_xor(mx, 2));
        mx = fmaxf(mx, __shfl_xor(mx, 4));
        mx = fmaxf(mx, __shfl_xor(mx, 8));
        const float e = __expf(v - mx);
        float sum = e;
        sum += __shfl_xor(sum, 1);
        sum += __shfl_xor(sum, 2);
        sum += __shfl_xor(sum, 4);
        sum += __shfl_xor(sum, 8);
        const float p = e / sum;

        if (lane < 16) {
            p_out[((size_t)(b * T_ + t)) * 16 + rl] = p;
            p_s[lt][rl] = p;
        }

        // enc passthrough: out[b,t,512:1024] = enc (exact f32)
        float4* ob = reinterpret_cast<float4*>(out + ((size_t)(b * T_ + t)) * 1024 + D_ + (size_t)lane * 8);
        ob[0] = e0; ob[1] = e1;
    }
    __syncthreads();

    // ---- stage C rows (reuse LDS), uniform trips, unroll 4 ----
    #pragma unroll 4
    for (int i = tid; i < NROWS * (D_ / 4); i += 256) {
        const int r = i >> 7;
        const int c = i & 127;
        int pos = t0 - (LEFT_ - 1) + r;
        pos = max(pos, 0);
        pos = min(pos, T_ - 1);
        const float4 v = reinterpret_cast<const float4*>(C + (size_t)symrow[pos] * D_)[c];
        *reinterpret_cast<uint2*>(&rows[r][c * 2]) =
            make_uint2(pack_bf2(v.x, v.y), pack_bf2(v.z, v.w));
    }
    __syncthreads();

    // ---- phase 2: compressed = sum_l p_l * C_row_l ----
    #pragma unroll
    for (int i = 0; i < 4; ++i) {
        const int lt = w + i * 4;
        const int t  = t0 + lt;
        const float4 q0 = *reinterpret_cast<const float4*>(&p_s[lt][0]);
        const float4 q1 = *reinterpret_cast<const float4*>(&p_s[lt][4]);
        const float4 q2 = *reinterpret_cast<const float4*>(&p_s[lt][8]);
        const float4 q3 = *reinterpret_cast<const float4*>(&p_s[lt][12]);
        const float pw[16] = { q0.x, q0.y, q0.z, q0.w, q1.x, q1.y, q1.z, q1.w,
                               q2.x, q2.y, q2.z, q2.w, q3.x, q3.y, q3.z, q3.w };

        float4 a0 = make_float4(0.f, 0.f, 0.f, 0.f);
        float4 a1 = make_float4(0.f, 0.f, 0.f, 0.f);
        #pragma unroll
        for (int l = 0; l < 16; ++l) {
            const uint4 c4 = *reinterpret_cast<const uint4*>(&rows[lt + l][lane * 4]);
            const float pl = pw[l];
            a0.x += pl * bf_lo(c4.x); a0.y += pl * bf_hi(c4.x);
            a0.z += pl * bf_lo(c4.y); a0.w += pl * bf_hi(c4.y);
            a1.x += pl * bf_lo(c4.z); a1.y += pl * bf_hi(c4.z);
            a1.z += pl * bf_lo(c4.w); a1.w += pl * bf_hi(c4.w);
        }
        float4* ob = reinterpret_cast<float4*>(out + ((size_t)(b * T_ + t)) * 1024 + (size_t)lane * 8);
        ob[0] = a0; ob[1] = a1;
    }
}

extern "C" void kernel_launch(void* const* d_in, const int* in_sizes, int n_in,
                              void* d_out, int out_size, void* d_ws, size_t ws_size,
                              hipStream_t stream) {
    const int*   symbols   = (const int*)d_in[0];
    const float* encodings = (const float*)d_in[1];
    const float* M         = (const float*)d_in[2];
    const float* C         = (const float*)d_in[3];
    float* out   = (float*)d_out;
    float* p_out = out + (size_t)B_ * T_ * 1024;   // concat order: output, then p

    dim3 grid(B_ * (T_ / BT));
    attn_cell_kernel<<<grid, 256, 0, stream>>>(symbols, encodings, M, C, out, p_out);
}

// Round 7
// 35.287 us; speedup vs baseline: 1.9674x; 1.0241x over previous
//
#include <hip/hip_runtime.h>
#include <hip/hip_bf16.h>

#define B_ 8
#define T_ 2048
#define V_ 256
#define D_ 512
#define LEFT_ 16
#define BT 16
#define NROWS 32

typedef short bf16x8 __attribute__((ext_vector_type(8)));
typedef float f32x4 __attribute__((ext_vector_type(4)));
typedef unsigned long long u64;

union FragU { unsigned u[4]; u64 ull[2]; bf16x8 v; };

__device__ __forceinline__ unsigned pack_bf2(float a, float b) {
    __hip_bfloat162 h = __float22bfloat162_rn(make_float2(a, b));
    union { __hip_bfloat162 h; unsigned u; } c; c.h = h; return c.u;
}
__device__ __forceinline__ unsigned short bf1(float x) {
    union { __hip_bfloat16 h; unsigned short s; } c; c.h = __float2bfloat16(x); return c.s;
}

// LDS layout:
//   [0, 32768)      M rows bf16 [32][512], 8B-granule XOR-swizzled by (row&7)
//   [32768, 41472)  Spart f32 [4][32][17]  (pad 17 -> conflict-free)
//   [0, 40960)      CT bf16 [512][40]  (overlaps above; staged after Spart consumed)
//   [41472, 42496)  P bf16 [16][32]  (zero-padded band matrix)
#define SMEM_BYTES 42496
#define SPART_OFF 32768
#define PLDS_OFF  41472

__global__ __launch_bounds__(256, 3)
void attn_cell_kernel(const int* __restrict__ symbols,
                      const float* __restrict__ encodings,
                      const float* __restrict__ M,
                      const float* __restrict__ C,
                      float* __restrict__ out,      // (B,T,1024)
                      float* __restrict__ p_out) {  // (B,T,16)
    __shared__ __align__(16) char smem[SMEM_BYTES];

    const int tid  = threadIdx.x;
    const int lane = tid & 63;
    const int w    = tid >> 6;      // wave 0..3
    const int q    = lane >> 4;     // 0..3
    const int t16  = lane & 15;

    const int blk = blockIdx.x;
    const int b   = blk >> 7;
    const int t0  = (blk & 127) * BT;
    const int* symrow = symbols + b * T_;
    const size_t rowbase = (size_t)(b * T_ + t0);

    // zero the P band matrix (256 u32 = 1 KB)
    ((unsigned*)(smem + PLDS_OFF))[tid] = 0u;

    // ---- stage M rows: bf16 [32][512], 8B granules XOR-swizzled by (row&7) ----
    {
        u64* r8 = (u64*)smem;
        #pragma unroll 2
        for (int i = tid; i < 2048; i += 256) {
            const int j = i >> 6;          // row 0..31
            const int g = i & 63;          // 16B granule (8 f32 source)
            int pos = t0 - (LEFT_ - 1) + j;
            pos = max(pos, 0); pos = min(pos, T_ - 1);
            const float* src = M + (size_t)symrow[pos] * D_ + g * 8;
            const float4 v0 = ((const float4*)src)[0];
            const float4 v1 = ((const float4*)src)[1];
            const u64 lo = (u64)pack_bf2(v0.x, v0.y) | ((u64)pack_bf2(v0.z, v0.w) << 32);
            const u64 hi = (u64)pack_bf2(v1.x, v1.y) | ((u64)pack_bf2(v1.z, v1.w) << 32);
            const int c = j & 7;
            r8[j * 128 + ((2 * g) ^ c)]     = lo;
            r8[j * 128 + ((2 * g + 1) ^ c)] = hi;
        }
    }
    __syncthreads();

    // ---- phase 1: S^T = Mrows · enc^T (MFMA), K=512 split across 4 waves ----
    {
        float4 lo[4], hi[4];
        const float* ebase = encodings + (rowbase + t16) * D_;
        float* obase = out + (rowbase + t16) * 1024 + D_;
        #pragma unroll
        for (int ks = 0; ks < 4; ++ks) {
            const int d0 = 128 * w + 32 * ks + 4 * q;
            lo[ks] = *(const float4*)(ebase + d0);
            hi[ks] = *(const float4*)(ebase + d0 + 16);
        }
        bf16x8 bfrag[4];
        #pragma unroll
        for (int ks = 0; ks < 4; ++ks) {
            const int d0 = 128 * w + 32 * ks + 4 * q;
            *(float4*)(obase + d0)      = lo[ks];   // exact f32 enc passthrough
            *(float4*)(obase + d0 + 16) = hi[ks];
            FragU u;
            u.u[0] = pack_bf2(lo[ks].x, lo[ks].y);
            u.u[1] = pack_bf2(lo[ks].z, lo[ks].w);
            u.u[2] = pack_bf2(hi[ks].x, hi[ks].y);
            u.u[3] = pack_bf2(hi[ks].z, hi[ks].w);
            bfrag[ks] = u.v;
        }
        const u64* r8 = (const u64*)smem;
        f32x4 acc0 = {0.f, 0.f, 0.f, 0.f}, acc1 = {0.f, 0.f, 0.f, 0.f};
        const int j0 = t16, j1 = t16 + 16;
        const int c0 = j0 & 7, c1 = j1 & 7;
        #pragma unroll
        for (int ks = 0; ks < 4; ++ks) {
            const int gb = 32 * w + 8 * ks + q;     // 8B-granule base this K-step
            FragU a0, a1;
            a0.ull[0] = r8[j0 * 128 + ((gb)     ^ c0)];
            a0.ull[1] = r8[j0 * 128 + ((gb + 4) ^ c0)];
            a1.ull[0] = r8[j1 * 128 + ((gb)     ^ c1)];
            a1.ull[1] = r8[j1 * 128 + ((gb + 4) ^ c1)];
            acc0 = __builtin_amdgcn_mfma_f32_16x16x32_bf16(a0.v, bfrag[ks], acc0, 0, 0, 0);
            acc1 = __builtin_amdgcn_mfma_f32_16x16x32_bf16(a1.v, bfrag[ks], acc1, 0, 0, 0);
        }
        float* spart = (float*)(smem + SPART_OFF);
        #pragma unroll
        for (int r = 0; r < 4; ++r) {
            spart[(w * 32 + 4 * q + r) * 17 + t16]      = acc0[r];
            spart[(w * 32 + 16 + 4 * q + r) * 17 + t16] = acc1[r];
        }
    }
    __syncthreads();

    // ---- softmax over the 16-band (one thread per (token, slot)) ----
    {
        const int l = t16;              // history slot
        const int t = 4 * w + q;        // token
        const int j = t + l;            // staged-row index
        const float* spart = (const float*)(smem + SPART_OFF);
        float v = spart[j * 17 + t] + spart[(32 + j) * 17 + t]
                + spart[(64 + j) * 17 + t] + spart[(96 + j) * 17 + t];
        float mx = v;
        mx = fmaxf(mx, __shfl_xor(mx, 1));
        mx = fmaxf(mx, __shfl_xor(mx, 2));
        mx = fmaxf(mx, __shfl_xor(mx, 4));
        mx = fmaxf(mx, __shfl_xor(mx, 8));
        const float e = __expf(v - mx);
        float sum = e;
        sum += __shfl_xor(sum, 1);
        sum += __shfl_xor(sum, 2);
        sum += __shfl_xor(sum, 4);
        sum += __shfl_xor(sum, 8);
        const float p = e / sum;
        p_out[(rowbase + t) * 16 + l] = p;
        ((unsigned short*)(smem + PLDS_OFF))[t * 32 + j] = bf1(p);
    }
    __syncthreads();

    // ---- stage C transposed: CT[512][40] bf16 (d-major) ----
    {
        unsigned short* ct = (unsigned short*)smem;
        #pragma unroll 2
        for (int i = tid; i < 2048; i += 256) {
            const int j = i & 31;          // staged row
            const int g = i >> 5;          // d granule 0..63
            int pos = t0 - (LEFT_ - 1) + j;
            pos = max(pos, 0); pos = min(pos, T_ - 1);
            const float* src = C + (size_t)symrow[pos] * D_ + g * 8;
            const float4 v0 = ((const float4*)src)[0];
            const float4 v1 = ((const float4*)src)[1];
            const int dbase = g * 8;
            ct[(dbase + 0) * 40 + j] = bf1(v0.x);
            ct[(dbase + 1) * 40 + j] = bf1(v0.y);
            ct[(dbase + 2) * 40 + j] = bf1(v0.z);
            ct[(dbase + 3) * 40 + j] = bf1(v0.w);
            ct[(dbase + 4) * 40 + j] = bf1(v1.x);
            ct[(dbase + 5) * 40 + j] = bf1(v1.y);
            ct[(dbase + 6) * 40 + j] = bf1(v1.z);
            ct[(dbase + 7) * 40 + j] = bf1(v1.w);
        }
    }
    __syncthreads();

    // ---- phase 2: O = P_band(16x32) · C_rows(32x512), 1 MFMA per 16x16 tile ----
    {
        const u64* p8 = (const u64*)(smem + PLDS_OFF);
        FragU ap;
        ap.ull[0] = p8[t16 * 8 + q];
        ap.ull[1] = p8[t16 * 8 + q + 4];
        const u64* ct8 = (const u64*)smem;
        #pragma unroll
        for (int m = 0; m < 8; ++m) {
            const int d = (w * 8 + m) * 16 + t16;
            FragU bc;
            bc.ull[0] = ct8[d * 10 + q];
            bc.ull[1] = ct8[d * 10 + q + 4];
            f32x4 acc = {0.f, 0.f, 0.f, 0.f};
            acc = __builtin_amdgcn_mfma_f32_16x16x32_bf16(ap.v, bc.v, acc, 0, 0, 0);
            #pragma unroll
            for (int r = 0; r < 4; ++r)
                out[(rowbase + 4 * q + r) * 1024 + d] = acc[r];
        }
    }
}

extern "C" void kernel_launch(void* const* d_in, const int* in_sizes, int n_in,
                              void* d_out, int out_size, void* d_ws, size_t ws_size,
                              hipStream_t stream) {
    const int*   symbols   = (const int*)d_in[0];
    const float* encodings = (const float*)d_in[1];
    const float* M         = (const float*)d_in[2];
    const float* C         = (const float*)d_in[3];
    float* out   = (float*)d_out;
    float* p_out = out + (size_t)B_ * T_ * 1024;   // concat order: output, then p

    dim3 grid(B_ * (T_ / BT));
    attn_cell_kernel<<<grid, 256, 0, stream>>>(symbols, encodings, M, C, out, p_out);
}

// Round 8
// 33.295 us; speedup vs baseline: 2.0852x; 1.0598x over previous
//
#include <hip/hip_runtime.h>

#define B_ 8
#define T_ 2048
#define V_ 256
#define D_ 512
#define LEFT_ 16
#define TPW 4                       // tokens per wave
#define NR (TPW + LEFT_ - 1)        // 19 window rows per wave

__device__ __forceinline__ constexpr int rev6(int x) {
    return (((x >> 0) & 1) << 5) | (((x >> 1) & 1) << 4) | (((x >> 2) & 1) << 3) |
           (((x >> 3) & 1) << 2) | (((x >> 4) & 1) << 1) | (((x >> 5) & 1) << 0);
}

__device__ __forceinline__ float dot8(const float4& m0, const float4& m1,
                                      const float4& e0, const float4& e1) {
    return m0.x * e0.x + m0.y * e0.y + m0.z * e0.z + m0.w * e0.w
         + m1.x * e1.x + m1.y * e1.y + m1.z * e1.z + m1.w * e1.w;
}

__global__ __launch_bounds__(256)
void attn_cell_kernel(const int* __restrict__ symbols,
                      const float* __restrict__ encodings,
                      const float* __restrict__ M,
                      const float* __restrict__ C,
                      float* __restrict__ out,      // (B,T,1024)
                      float* __restrict__ p_out) {  // (B,T,16)
    const int tid  = threadIdx.x;
    const int lane = tid & 63;
    const int w    = tid >> 6;

    const int blk = blockIdx.x;
    const int b   = blk >> 7;                       // 128 blocks per batch row
    const int tb  = (blk & 127) * 16 + w * TPW;     // wave's first token
    const int* symrow = symbols + b * T_;
    const size_t rowbase = (size_t)b * T_ + tb;
    const int dof = lane * 8;                       // this lane's 8 dims

    // symbols for the 19-row window (wave-uniform -> SGPRs)
    int syms[NR];
    #pragma unroll
    for (int i = 0; i < NR; ++i) {
        int pos = tb - (LEFT_ - 1) + i;
        pos = max(pos, 0);
        syms[i] = symrow[pos];
    }

    // encodings for the 4 tokens (kept in regs; reused for passthrough store)
    float4 e0[TPW], e1[TPW];
    #pragma unroll
    for (int tk = 0; tk < TPW; ++tk) {
        const float* e = encodings + (rowbase + tk) * D_ + dof;
        e0[tk] = *(const float4*)e;
        e1[tk] = *(const float4*)(e + 4);
    }

    // ---- phase A: per-lane partial scores for all 64 (token, slot) pairs ----
    float s[64];
    #pragma unroll
    for (int v = 0; v < 64; ++v) s[v] = 0.f;

    #pragma unroll
    for (int i = 0; i < NR; ++i) {
        const float* mr = M + (size_t)syms[i] * D_ + dof;
        const float4 m0 = *(const float4*)mr;
        const float4 m1 = *(const float4*)(mr + 4);
        #pragma unroll
        for (int tk = 0; tk < TPW; ++tk) {
            const int sl = i - tk;
            if (sl >= 0 && sl < 16)
                s[(tk << 4) | sl] += dot8(m0, m1, e0[tk], e1[tk]);
        }
    }

    // ---- folding butterfly: 63 shfl, 64 values -> 1 per lane (idx = rev6(lane)) ----
    #pragma unroll
    for (int k = 0; k < 32; ++k) {
        const float lo = s[k], hi = s[k + 32];
        const float sd = (lane & 1) ? lo : hi;
        const float rv = __shfl_xor(sd, 1);
        s[k] = (lane & 1) ? hi + rv : lo + rv;
    }
    #pragma unroll
    for (int k = 0; k < 16; ++k) {
        const float lo = s[k], hi = s[k + 16];
        const float sd = (lane & 2) ? lo : hi;
        const float rv = __shfl_xor(sd, 2);
        s[k] = (lane & 2) ? hi + rv : lo + rv;
    }
    #pragma unroll
    for (int k = 0; k < 8; ++k) {
        const float lo = s[k], hi = s[k + 8];
        const float sd = (lane & 4) ? lo : hi;
        const float rv = __shfl_xor(sd, 4);
        s[k] = (lane & 4) ? hi + rv : lo + rv;
    }
    #pragma unroll
    for (int k = 0; k < 4; ++k) {
        const float lo = s[k], hi = s[k + 4];
        const float sd = (lane & 8) ? lo : hi;
        const float rv = __shfl_xor(sd, 8);
        s[k] = (lane & 8) ? hi + rv : lo + rv;
    }
    #pragma unroll
    for (int k = 0; k < 2; ++k) {
        const float lo = s[k], hi = s[k + 2];
        const float sd = (lane & 16) ? lo : hi;
        const float rv = __shfl_xor(sd, 16);
        s[k] = (lane & 16) ? hi + rv : lo + rv;
    }
    {
        const float lo = s[0], hi = s[1];
        const float sd = (lane & 32) ? lo : hi;
        const float rv = __shfl_xor(sd, 32);
        s[0] = (lane & 32) ? hi + rv : lo + rv;
    }
    const float v = s[0];   // full score for idx = rev6(lane): tk = idx>>4, sl = idx&15

    // ---- softmax across each token's 16 lanes (lanes sharing lane&3) ----
    float mx = v;
    mx = fmaxf(mx, __shfl_xor(mx, 4));
    mx = fmaxf(mx, __shfl_xor(mx, 8));
    mx = fmaxf(mx, __shfl_xor(mx, 16));
    mx = fmaxf(mx, __shfl_xor(mx, 32));
    const float ex = __expf(v - mx);
    float sum = ex;
    sum += __shfl_xor(sum, 4);
    sum += __shfl_xor(sum, 8);
    sum += __shfl_xor(sum, 16);
    sum += __shfl_xor(sum, 32);
    const float p = ex / sum;

    // write p: lane owns (tk_o, sl_o)
    {
        const int idx  = rev6(lane);
        const int tk_o = idx >> 4;
        const int sl_o = idx & 15;
        p_out[(rowbase + tk_o) * 16 + sl_o] = p;
    }

    // ---- phase B: compressed = sum_sl p * C_row, p broadcast via const-lane shfl ----
    float4 a0[TPW], a1[TPW];
    #pragma unroll
    for (int tk = 0; tk < TPW; ++tk) {
        a0[tk] = make_float4(0.f, 0.f, 0.f, 0.f);
        a1[tk] = make_float4(0.f, 0.f, 0.f, 0.f);
    }

    #pragma unroll
    for (int i = 0; i < NR; ++i) {
        const float* cr = C + (size_t)syms[i] * D_ + dof;
        const float4 c0 = *(const float4*)cr;
        const float4 c1 = *(const float4*)(cr + 4);
        #pragma unroll
        for (int tk = 0; tk < TPW; ++tk) {
            const int sl = i - tk;
            if (sl >= 0 && sl < 16) {
                const float pb = __shfl(p, rev6((tk << 4) | sl));
                a0[tk].x += pb * c0.x; a0[tk].y += pb * c0.y;
                a0[tk].z += pb * c0.z; a0[tk].w += pb * c0.w;
                a1[tk].x += pb * c1.x; a1[tk].y += pb * c1.y;
                a1[tk].z += pb * c1.z; a1[tk].w += pb * c1.w;
            }
        }
    }

    // ---- stores: compressed + exact enc passthrough, all wave-contiguous ----
    #pragma unroll
    for (int tk = 0; tk < TPW; ++tk) {
        float* ob = out + (rowbase + tk) * 1024 + dof;
        *(float4*)ob       = a0[tk];
        *(float4*)(ob + 4) = a1[tk];
        *(float4*)(ob + D_)     = e0[tk];
        *(float4*)(ob + D_ + 4) = e1[tk];
    }
}

extern "C" void kernel_launch(void* const* d_in, const int* in_sizes, int n_in,
                              void* d_out, int out_size, void* d_ws, size_t ws_size,
                              hipStream_t stream) {
    const int*   symbols   = (const int*)d_in[0];
    const float* encodings = (const float*)d_in[1];
    const float* M         = (const float*)d_in[2];
    const float* C         = (const float*)d_in[3];
    float* out   = (float*)d_out;
    float* p_out = out + (size_t)B_ * T_ * 1024;   // concat order: output, then p

    dim3 grid(B_ * (T_ / 16));                     // 16 tokens per 4-wave block
    attn_cell_kernel<<<grid, 256, 0, stream>>>(symbols, encodings, M, C, out, p_out);
}